// Round 14
// baseline (82.522 us; speedup 1.0000x reference)
//
#include <hip/hip_runtime.h>
#include <math.h>

#define TLEN (1 << 20)
#define SB 32              // reset-chain sub-chunk
#define NSB (TLEN / SB)    // 32768 sub-chunks
#define SCB 512            // maps per scan block
#define NSCB (NSB / SCB)   // 64 scan blocks
#define THRESH 1e-4f
#define IDMAP 0x00FAC688u  // packed identity map: entry g -> g (3 bits each)

#define WWORDS (SCB * SB + 8)      // 16392 staged Z words (8 lead slots)
#define WPAD(i) ((i) + ((i) >> 5)) // +1 word per 32: kills stride-32 bank conflicts
#define LDSW WPAD(WWORDS)

#pragma clang fp contract(off)

// consts layout: 0:w1 1:w2 2:w3 3:w4 4:dt1 5:dt2 6:d2t1 7:d2t2 8:2*w4

// The canonical 32-output chunk program (round-12 PROVEN, verbatim).
#define CHUNK55(OFS, OUTARR) {                                                 \
        const float4* xp_ = (const float4*)(X + (OFS) - 24);                   \
        float xa_[56];                                                         \
        _Pragma("unroll")                                                      \
        for (int q_ = 0; q_ < 14; ++q_) {                                      \
            float4 v_ = xp_[q_];                                               \
            xa_[4 * q_ + 0] = v_.x; xa_[4 * q_ + 1] = v_.y;                    \
            xa_[4 * q_ + 2] = v_.z; xa_[4 * q_ + 3] = v_.w;                    \
        }                                                                      \
        float h_ = 0.0f;                                                       \
        _Pragma("unroll")                                                      \
        for (int p_ = 0; p_ < 55; ++p_) {                                      \
            float x_ = xa_[p_];                                                \
            float t1_ = w1 * x_;                                               \
            float t2_ = w2 * h_;                                               \
            float s1_ = t1_ + t2_;                                             \
            float t3_ = (w3 * x_) * x_;                                        \
            float s2_ = s1_ + t3_;                                             \
            float t4_ = (w4 * h_) * h_;                                        \
            h_ = s2_ + t4_;                                                    \
            if (p_ >= 23) OUTARR[p_ - 23] = h_;                                \
        }                                                                      \
    }

// K1: Z + tables + scan in one launch (round-12 PROVEN, verbatim).
__global__ void __launch_bounds__(512) k_zts(const float* __restrict__ P,
                                             const float* __restrict__ X,
                                             float* __restrict__ c,
                                             float* __restrict__ Z,
                                             unsigned int* __restrict__ L32,
                                             unsigned int* __restrict__ BT) {
#pragma clang fp contract(off)
    __shared__ float sc[4];
    __shared__ float zw[LDSW];
    __shared__ unsigned int buf[2][SCB];
    int t = threadIdx.x;
    int b = blockIdx.x;
    if (t == 0) {
        float tw1 = (float)tanh((double)P[0]);
        float tw2 = (float)tanh((double)P[1]);
        sc[0] = tw1; sc[1] = tw2; sc[2] = P[2]; sc[3] = P[3];
        if (b == 0) {
            float dt1 = 1.0f - tw1 * tw1;
            float dt2 = 1.0f - tw2 * tw2;
            c[0] = tw1; c[1] = tw2; c[2] = P[2]; c[3] = P[3];
            c[4] = dt1; c[5] = dt2;
            c[6] = (-2.0f * tw1) * dt1; c[7] = (-2.0f * tw2) * dt2;
            c[8] = 2.0f * P[3];
        }
    }
    __syncthreads();
    float w1 = sc[0], w2 = sc[1], w3 = sc[2], w4 = sc[3];
    float w42 = 2.0f * w4;
    long gi = (long)b * SCB + t;
    long o = gi * 32;
    float out[32];
    if (gi == 0) {
        float h = 0.0f;
        out[0] = 0.0f;                       // Z[0]
        for (int k = 0; k < 31; ++k) {
            float x = X[k];
            float t1 = w1 * x;
            float t2 = w2 * h;
            float s1 = t1 + t2;
            float t3 = (w3 * x) * x;
            float s2 = s1 + t3;
            float t4 = (w4 * h) * h;
            h = s2 + t4;
            out[k + 1] = h;
        }
    } else {
        CHUNK55(o, out);
    }
#pragma unroll
    for (int q = 0; q < 8; ++q)
        *(float4*)(Z + o + 4 * q) = make_float4(out[4 * q], out[4 * q + 1],
                                                out[4 * q + 2], out[4 * q + 3]);
    int rbase = t * 32 + 8;
#pragma unroll
    for (int k = 0; k < 32; ++k) zw[WPAD(rbase + k)] = out[k];
    if (t == 0 && b > 0) {
        long op = (long)b * (SCB * SB) - 32;   // previous chunk owner's offset
        float pout[32];
        CHUNK55(op, pout);
#pragma unroll
        for (int q = 0; q < 7; ++q) zw[WPAD(1 + q)] = pout[25 + q];
    }
    __syncthreads();
    unsigned int m32;
    if (gi < NSB - 1) {
        float d[8]; int last[8];
#pragma unroll
        for (int g = 0; g < 8; ++g) { d[g] = 1.0f; last[g] = -g; }
        if (gi == 0) {
#pragma unroll
            for (int g = 0; g < 8; ++g) last[g] = 0;
            for (int k = 0; k < 32; ++k) {
                float fa = fabsf(w2 + w42 * zw[WPAD(rbase + k)]);
#pragma unroll
                for (int g = 0; g < 8; ++g) {
                    d[g] = d[g] * fa;
                    if (d[g] < THRESH) { last[g] = k + 1; d[g] = 1.0f; }
                }
            }
        } else {
#pragma unroll
            for (int p = 0; p < 7; ++p) {
                float fa = fabsf(w2 + w42 * zw[WPAD(rbase + p - 7)]);
#pragma unroll
                for (int g = 7 - p; g < 8; ++g) {
                    d[g] = d[g] * fa;
                    if (d[g] < THRESH) { last[g] = p - 6; d[g] = 1.0f; }
                }
            }
            for (int k = 0; k < 32; ++k) {
                float fa = fabsf(w2 + w42 * zw[WPAD(rbase + k)]);
#pragma unroll
                for (int g = 0; g < 8; ++g) {
                    d[g] = d[g] * fa;
                    if (d[g] < THRESH) { last[g] = k + 1; d[g] = 1.0f; }
                }
            }
        }
        m32 = 0;
#pragma unroll
        for (int g = 0; g < 8; ++g) {
            int delta = 32 - last[g]; if (delta > 7) delta = 7;
            m32 |= (unsigned int)delta << (3 * g);
        }
    } else {
        m32 = IDMAP;
    }
    buf[0][t] = m32;
    __syncthreads();
    int cur = 0;
    for (int off = 1; off < SCB; off <<= 1) {
        unsigned int hi = buf[cur][t];
        unsigned int r;
        if (t >= off) {
            unsigned int lo = buf[cur][t - off];
            r = 0;
#pragma unroll
            for (int g = 0; g < 8; ++g) {
                unsigned int lg = (lo >> (3 * g)) & 7u;
                r |= ((hi >> (3 * lg)) & 7u) << (3 * g);
            }
        } else {
            r = hi;
        }
        buf[cur ^ 1][t] = r;
        __syncthreads();
        cur ^= 1;
    }
    L32[gi] = buf[cur][t];
    if (t == SCB - 1) BT[b] = buf[cur][t];
}

// K2: age + jh with 4-lane redundant compute for line-grain stores.
// Block = 1024 threads = 256 outputs (4 lanes/output). Threads 0-7: round-13
// PROVEN age replay -> LDS. Lanes 4i+k all compute output i's J,H (identical op
// sequence -> identical bits), then lane 4i+k stores H-quadrant k at f4-index
// B*1024 + t (consecutive per lane -> full-line writes) and J component k as a
// scalar at float-index B*1024 + t (fully dense).
__global__ void __launch_bounds__(1024) k_jh3(const float* __restrict__ X,
                                              const float* __restrict__ Z,
                                              const float* __restrict__ c,
                                              const unsigned int* __restrict__ L32,
                                              const unsigned int* __restrict__ BT,
                                              float* __restrict__ Jout,
                                              float* __restrict__ Hout) {
#pragma clang fp contract(off)
    __shared__ unsigned int sBT[NSCB];
    __shared__ unsigned char ages[256];
    int t = threadIdx.x;
    int B = blockIdx.x;
    float w2 = c[1], dt1 = c[4], dt2 = c[5], d2t1 = c[6], d2t2 = c[7], w42 = c[8];
    if (t < NSCB) sBT[t] = BT[t];
    __syncthreads();
    if (t < 8) {
        int i = B * 8 + t;
        int e = 0;
        if (i > 0) {
            int bp = (i - 1) >> 9;           // / SCB
            unsigned int g = 0;
            for (int k = 0; k < bp; ++k) g = (sBT[k] >> (3 * g)) & 7u;
            e = (int)((L32[i - 1] >> (3 * g)) & 7u);
        }
        long ci = (long)i * SB;
        long r = ci - e;
        float d = 1.0f;
        long last = r;
        for (long m = r + 1; m <= ci; ++m) {
            float a = w2 + w42 * Z[m - 1];
            d = d * fabsf(a);
            if (d < THRESH) { last = m; d = 1.0f; }
        }
        ages[t * 32] = (unsigned char)(ci - last);
        for (int k = 1; k < SB; ++k) {
            long m = ci + k;
            float a = w2 + w42 * Z[m - 1];
            d = d * fabsf(a);
            if (d < THRESH) { last = m; d = 1.0f; }
            ages[t * 32 + k] = (unsigned char)(m - last);
        }
    }
    __syncthreads();
    int o = t >> 2;                        // output within block (0..255)
    int k = t & 3;                         // quadrant / component
    long q = (long)B * 256 + o;
    int a = (int)ages[o];
    float J0 = 0, J1 = 0, J2 = 0, J3 = 0;
    float H00 = 0, H01 = 0, H03 = 0, H11 = 0, H12 = 0, H13 = 0, H23 = 0, H33 = 0;
    if (a > 0) {
        long m0 = q - a + 1;
        {   // JH_SIMPLE(m0): fresh state after reset (round-13 proven)
            float x = X[m0 - 1];
            float h = Z[m0 - 1];
            H00 = x * d2t1; H11 = h * d2t2;
            J0 = x * dt1; J1 = h * dt2; J2 = x * x; J3 = h * h;
        }
        for (long m = m0 + 1; m <= q; ++m) {   // JH_STEP (round-13 proven)
            float x = X[m - 1];
            float h = Z[m - 1];
            float av = w2 + w42 * h;
            float g3 = 2.0f * h;
            float g1J0 = dt2 * J0, g1J1 = dt2 * J1, g1J2 = dt2 * J2, g1J3 = dt2 * J3;
            float g3J0 = g3 * J0, g3J1 = g3 * J1, g3J2 = g3 * J2, g3J3 = g3 * J3;
            float n00 = (x * d2t1) + av * H00;
            float n01 = g1J0 + av * H01;
            float n03 = g3J0 + av * H03;
            float n11 = (((h * d2t2) + g1J1) + g1J1) + av * H11;
            float n12 = g1J2 + av * H12;
            float n13 = (g1J3 + g3J1) + av * H13;
            float n23 = g3J2 + av * H23;
            float n33 = (g3J3 + g3J3) + av * H33;
            H00 = n00; H01 = n01; H03 = n03; H11 = n11;
            H12 = n12; H13 = n13; H23 = n23; H33 = n33;
            J0 = (x * dt1) + av * J0;
            J1 = (h * dt2) + av * J1;
            J2 = (x * x) + av * J2;
            J3 = (h * h) + av * J3;
        }
    }
    float4 hv;
    if (k == 0)      hv = make_float4(H00, H01, 0.0f, H03);
    else if (k == 1) hv = make_float4(H01, H11, H12, H13);
    else if (k == 2) hv = make_float4(0.0f, H12, 0.0f, H23);
    else             hv = make_float4(H03, H13, H23, H33);
    ((float4*)Hout)[(long)B * 1024 + t] = hv;                  // lane-consecutive f4
    float jv = (k == 0) ? J0 : (k == 1) ? J1 : (k == 2) ? J2 : J3;
    Jout[(long)B * 1024 + t] = jv;                             // lane-consecutive f32
}

extern "C" void kernel_launch(void* const* d_in, const int* in_sizes, int n_in,
                              void* d_out, int out_size, void* d_ws, size_t ws_size,
                              hipStream_t stream) {
    const float* X = (const float*)d_in[0];
    const float* P = (const float*)d_in[1];
    float* out = (float*)d_out;
    float* Z = out;                       // [T]
    float* Jout = out + (long)TLEN;       // [T,4]
    float* Hout = out + 5l * TLEN;        // [T,4,4]

    char* ws = (char*)d_ws;
    float* consts = (float*)ws;                                    // @0, 64 B
    unsigned int* BT = (unsigned int*)(ws + 64);                   // 64 dwords
    unsigned int* L32 = (unsigned int*)(ws + 512);                 // 128 KB

    hipLaunchKernelGGL(k_zts, dim3(NSCB), dim3(SCB), 0, stream,
                       P, X, consts, Z, L32, BT);
    hipLaunchKernelGGL(k_jh3, dim3(TLEN / 256), dim3(1024), 0, stream,
                       X, Z, consts, L32, BT, Jout, Hout);
}

// Round 15
// 43.894 us; speedup vs baseline: 1.8800x; 1.8800x over previous
//
#include <hip/hip_runtime.h>
#include <math.h>

#define TLEN (1 << 20)
#define SB 32              // reset-chain sub-chunk
#define NSB (TLEN / SB)    // 32768 sub-chunks
#define SCB 512            // maps per scan block
#define NSCB (NSB / SCB)   // 64 scan blocks
#define THRESH 1e-4f
#define IDMAP 0x00FAC688u  // packed identity map: entry g -> g (3 bits each)

#define WWORDS (SCB * SB + 8)      // 16392 staged Z words (8 lead slots)
#define WPAD(i) ((i) + ((i) >> 5)) // +1 word per 32: kills stride-32 bank conflicts
#define LDSW WPAD(WWORDS)

#pragma clang fp contract(off)

// consts layout: 0:w1 1:w2 2:w3 3:w4 4:dt1 5:dt2 6:d2t1 7:d2t2 8:2*w4

// The canonical 32-output chunk program (round-12 PROVEN, verbatim).
#define CHUNK55(OFS, OUTARR) {                                                 \
        const float4* xp_ = (const float4*)(X + (OFS) - 24);                   \
        float xa_[56];                                                         \
        _Pragma("unroll")                                                      \
        for (int q_ = 0; q_ < 14; ++q_) {                                      \
            float4 v_ = xp_[q_];                                               \
            xa_[4 * q_ + 0] = v_.x; xa_[4 * q_ + 1] = v_.y;                    \
            xa_[4 * q_ + 2] = v_.z; xa_[4 * q_ + 3] = v_.w;                    \
        }                                                                      \
        float h_ = 0.0f;                                                       \
        _Pragma("unroll")                                                      \
        for (int p_ = 0; p_ < 55; ++p_) {                                      \
            float x_ = xa_[p_];                                                \
            float t1_ = w1 * x_;                                               \
            float t2_ = w2 * h_;                                               \
            float s1_ = t1_ + t2_;                                             \
            float t3_ = (w3 * x_) * x_;                                        \
            float s2_ = s1_ + t3_;                                             \
            float t4_ = (w4 * h_) * h_;                                        \
            h_ = s2_ + t4_;                                                    \
            if (p_ >= 23) OUTARR[p_ - 23] = h_;                                \
        }                                                                      \
    }

// K1: Z + tables + scan in one launch (round-12 PROVEN, verbatim).
__global__ void __launch_bounds__(512) k_zts(const float* __restrict__ P,
                                             const float* __restrict__ X,
                                             float* __restrict__ c,
                                             float* __restrict__ Z,
                                             unsigned int* __restrict__ L32,
                                             unsigned int* __restrict__ BT) {
#pragma clang fp contract(off)
    __shared__ float sc[4];
    __shared__ float zw[LDSW];
    __shared__ unsigned int buf[2][SCB];
    int t = threadIdx.x;
    int b = blockIdx.x;
    if (t == 0) {
        float tw1 = (float)tanh((double)P[0]);
        float tw2 = (float)tanh((double)P[1]);
        sc[0] = tw1; sc[1] = tw2; sc[2] = P[2]; sc[3] = P[3];
        if (b == 0) {
            float dt1 = 1.0f - tw1 * tw1;
            float dt2 = 1.0f - tw2 * tw2;
            c[0] = tw1; c[1] = tw2; c[2] = P[2]; c[3] = P[3];
            c[4] = dt1; c[5] = dt2;
            c[6] = (-2.0f * tw1) * dt1; c[7] = (-2.0f * tw2) * dt2;
            c[8] = 2.0f * P[3];
        }
    }
    __syncthreads();
    float w1 = sc[0], w2 = sc[1], w3 = sc[2], w4 = sc[3];
    float w42 = 2.0f * w4;
    long gi = (long)b * SCB + t;
    long o = gi * 32;
    float out[32];
    if (gi == 0) {
        float h = 0.0f;
        out[0] = 0.0f;                       // Z[0]
        for (int k = 0; k < 31; ++k) {
            float x = X[k];
            float t1 = w1 * x;
            float t2 = w2 * h;
            float s1 = t1 + t2;
            float t3 = (w3 * x) * x;
            float s2 = s1 + t3;
            float t4 = (w4 * h) * h;
            h = s2 + t4;
            out[k + 1] = h;
        }
    } else {
        CHUNK55(o, out);
    }
#pragma unroll
    for (int q = 0; q < 8; ++q)
        *(float4*)(Z + o + 4 * q) = make_float4(out[4 * q], out[4 * q + 1],
                                                out[4 * q + 2], out[4 * q + 3]);
    int rbase = t * 32 + 8;
#pragma unroll
    for (int k = 0; k < 32; ++k) zw[WPAD(rbase + k)] = out[k];
    if (t == 0 && b > 0) {
        long op = (long)b * (SCB * SB) - 32;   // previous chunk owner's offset
        float pout[32];
        CHUNK55(op, pout);
#pragma unroll
        for (int q = 0; q < 7; ++q) zw[WPAD(1 + q)] = pout[25 + q];
    }
    __syncthreads();
    unsigned int m32;
    if (gi < NSB - 1) {
        float d[8]; int last[8];
#pragma unroll
        for (int g = 0; g < 8; ++g) { d[g] = 1.0f; last[g] = -g; }
        if (gi == 0) {
#pragma unroll
            for (int g = 0; g < 8; ++g) last[g] = 0;
            for (int k = 0; k < 32; ++k) {
                float fa = fabsf(w2 + w42 * zw[WPAD(rbase + k)]);
#pragma unroll
                for (int g = 0; g < 8; ++g) {
                    d[g] = d[g] * fa;
                    if (d[g] < THRESH) { last[g] = k + 1; d[g] = 1.0f; }
                }
            }
        } else {
#pragma unroll
            for (int p = 0; p < 7; ++p) {
                float fa = fabsf(w2 + w42 * zw[WPAD(rbase + p - 7)]);
#pragma unroll
                for (int g = 7 - p; g < 8; ++g) {
                    d[g] = d[g] * fa;
                    if (d[g] < THRESH) { last[g] = p - 6; d[g] = 1.0f; }
                }
            }
            for (int k = 0; k < 32; ++k) {
                float fa = fabsf(w2 + w42 * zw[WPAD(rbase + k)]);
#pragma unroll
                for (int g = 0; g < 8; ++g) {
                    d[g] = d[g] * fa;
                    if (d[g] < THRESH) { last[g] = k + 1; d[g] = 1.0f; }
                }
            }
        }
        m32 = 0;
#pragma unroll
        for (int g = 0; g < 8; ++g) {
            int delta = 32 - last[g]; if (delta > 7) delta = 7;
            m32 |= (unsigned int)delta << (3 * g);
        }
    } else {
        m32 = IDMAP;
    }
    buf[0][t] = m32;
    __syncthreads();
    int cur = 0;
    for (int off = 1; off < SCB; off <<= 1) {
        unsigned int hi = buf[cur][t];
        unsigned int r;
        if (t >= off) {
            unsigned int lo = buf[cur][t - off];
            r = 0;
#pragma unroll
            for (int g = 0; g < 8; ++g) {
                unsigned int lg = (lo >> (3 * g)) & 7u;
                r |= ((hi >> (3 * lg)) & 7u) << (3 * g);
            }
        } else {
            r = hi;
        }
        buf[cur ^ 1][t] = r;
        __syncthreads();
        cur ^= 1;
    }
    L32[gi] = buf[cur][t];
    if (t == SCB - 1) BT[b] = buf[cur][t];
}

// K2: age + jh, 1 output/thread compute (round-13 PROVEN bodies), H exchanged
// through LDS (stride-17 pad -> 2-way conflicts = free) so global H stores are
// lane-consecutive float4s (full 64-B lines, the request profile r14 validated).
// J stores were already dense (16 B/lane consecutive) -> direct.
__global__ void __launch_bounds__(256) k_jh4(const float* __restrict__ X,
                                             const float* __restrict__ Z,
                                             const float* __restrict__ c,
                                             const unsigned int* __restrict__ L32,
                                             const unsigned int* __restrict__ BT,
                                             float* __restrict__ Jout,
                                             float* __restrict__ Hout) {
#pragma clang fp contract(off)
    __shared__ unsigned int sBT[NSCB];
    __shared__ unsigned char ages[256];
    __shared__ float hx[256 * 17];          // [o*17 + c], c=0..15
    int t = threadIdx.x;
    int B = blockIdx.x;
    float w2 = c[1], dt1 = c[4], dt2 = c[5], d2t1 = c[6], d2t2 = c[7], w42 = c[8];
    if (t < NSCB) sBT[t] = BT[t];
    __syncthreads();
    if (t < 8) {
        int i = B * 8 + t;
        int e = 0;
        if (i > 0) {
            int bp = (i - 1) >> 9;           // / SCB
            unsigned int g = 0;
            for (int k = 0; k < bp; ++k) g = (sBT[k] >> (3 * g)) & 7u;
            e = (int)((L32[i - 1] >> (3 * g)) & 7u);
        }
        long ci = (long)i * SB;
        long r = ci - e;
        float d = 1.0f;
        long last = r;
        for (long m = r + 1; m <= ci; ++m) {
            float a = w2 + w42 * Z[m - 1];
            d = d * fabsf(a);
            if (d < THRESH) { last = m; d = 1.0f; }
        }
        ages[t * 32] = (unsigned char)(ci - last);
        for (int k = 1; k < SB; ++k) {
            long m = ci + k;
            float a = w2 + w42 * Z[m - 1];
            d = d * fabsf(a);
            if (d < THRESH) { last = m; d = 1.0f; }
            ages[t * 32 + k] = (unsigned char)(m - last);
        }
    }
    __syncthreads();
    long q = (long)B * 256 + t;
    int a = (int)ages[t];
    float J0 = 0, J1 = 0, J2 = 0, J3 = 0;
    float H00 = 0, H01 = 0, H03 = 0, H11 = 0, H12 = 0, H13 = 0, H23 = 0, H33 = 0;
    if (a > 0) {
        long m0 = q - a + 1;
        {   // JH_SIMPLE(m0): fresh state after reset (round-13 proven)
            float x = X[m0 - 1];
            float h = Z[m0 - 1];
            H00 = x * d2t1; H11 = h * d2t2;
            J0 = x * dt1; J1 = h * dt2; J2 = x * x; J3 = h * h;
        }
        for (long m = m0 + 1; m <= q; ++m) {   // JH_STEP (round-13 proven)
            float x = X[m - 1];
            float h = Z[m - 1];
            float av = w2 + w42 * h;
            float g3 = 2.0f * h;
            float g1J0 = dt2 * J0, g1J1 = dt2 * J1, g1J2 = dt2 * J2, g1J3 = dt2 * J3;
            float g3J0 = g3 * J0, g3J1 = g3 * J1, g3J2 = g3 * J2, g3J3 = g3 * J3;
            float n00 = (x * d2t1) + av * H00;
            float n01 = g1J0 + av * H01;
            float n03 = g3J0 + av * H03;
            float n11 = (((h * d2t2) + g1J1) + g1J1) + av * H11;
            float n12 = g1J2 + av * H12;
            float n13 = (g1J3 + g3J1) + av * H13;
            float n23 = g3J2 + av * H23;
            float n33 = (g3J3 + g3J3) + av * H33;
            H00 = n00; H01 = n01; H03 = n03; H11 = n11;
            H12 = n12; H13 = n13; H23 = n23; H33 = n33;
            J0 = (x * dt1) + av * J0;
            J1 = (h * dt2) + av * J1;
            J2 = (x * x) + av * J2;
            J3 = (h * h) + av * J3;
        }
    }
    // J: direct store, already dense (lane-consecutive 16 B)
    *((float4*)(Jout + 4 * q)) = make_float4(J0, J1, J2, J3);
    // H: stage row-major 16 values into padded LDS
    float* hr = hx + t * 17;
    hr[0]  = H00; hr[1]  = H01; hr[2]  = 0.0f; hr[3]  = H03;
    hr[4]  = H01; hr[5]  = H11; hr[6]  = H12;  hr[7]  = H13;
    hr[8]  = 0.0f; hr[9] = H12; hr[10] = 0.0f; hr[11] = H23;
    hr[12] = H03; hr[13] = H13; hr[14] = H23;  hr[15] = H33;
    __syncthreads();
    // dense line-grain stores: thread t emits block f4-slots t, t+256, t+512, t+768
    float4* Hp = (float4*)Hout + (long)B * 1024;
#pragma unroll
    for (int r = 0; r < 4; ++r) {
        int f = 256 * r + t;                // block-local f4 index
        int o = f >> 2;                     // output within block
        int cc = (f & 3) * 4;               // first component of this f4
        const float* s = hx + o * 17 + cc;
        Hp[f] = make_float4(s[0], s[1], s[2], s[3]);
    }
}

extern "C" void kernel_launch(void* const* d_in, const int* in_sizes, int n_in,
                              void* d_out, int out_size, void* d_ws, size_t ws_size,
                              hipStream_t stream) {
    const float* X = (const float*)d_in[0];
    const float* P = (const float*)d_in[1];
    float* out = (float*)d_out;
    float* Z = out;                       // [T]
    float* Jout = out + (long)TLEN;       // [T,4]
    float* Hout = out + 5l * TLEN;        // [T,4,4]

    char* ws = (char*)d_ws;
    float* consts = (float*)ws;                                    // @0, 64 B
    unsigned int* BT = (unsigned int*)(ws + 64);                   // 64 dwords
    unsigned int* L32 = (unsigned int*)(ws + 512);                 // 128 KB

    hipLaunchKernelGGL(k_zts, dim3(NSCB), dim3(SCB), 0, stream,
                       P, X, consts, Z, L32, BT);
    hipLaunchKernelGGL(k_jh4, dim3(TLEN / 256), dim3(256), 0, stream,
                       X, Z, consts, L32, BT, Jout, Hout);
}